// Round 4
// baseline (628.934 us; speedup 1.0000x reference)
//
#include <hip/hip_runtime.h>

// SparseGCNConv: out = segment_sum(norm * f[src], dst, N) @ W^T + bias
// R9: replace the two-level bucket sort (hist/scan/bin/sort: ~250us by
// subtraction, bufA round-trip + 12.8M LDS atomics) with direct per-node
// placement: histn (3.2M global atomics into 400KB L2-resident counts) ->
// scan100k (single-block coalesced int4 shfl scan of 100K counts) ->
// place (atomicAdd(&cur[dst]) -> write bufB at final position).
// gemm (MFMA bf16->f16 g-matrix) and pull (depth-2 pipelined fmix gather,
// 106us, fabric-bound) unchanged from R8.

#define NN    100000
#define NE    3200000
#define D     128
#define NTILE 6250  // NN/16 node tiles (exact)

typedef __attribute__((ext_vector_type(8))) short bf16x8;
typedef __attribute__((ext_vector_type(4))) float f32x4;

static __device__ __forceinline__ unsigned short f2bf(float x) {
  unsigned u = __float_as_uint(x);
  u += 0x7FFFu + ((u >> 16) & 1u);  // RTNE
  return (unsigned short)(u >> 16);
}

// 8 channels of one gathered f16 row-slice, scaled by nr, into f32 accs.
static __device__ __forceinline__ void fmix8(float* acc, uint4 q, float nr) {
  asm("v_fma_mix_f32 %0, %1, %2, %0 op_sel:[0,0,0] op_sel_hi:[1,0,0]"
      : "+v"(acc[0]) : "v"(q.x), "v"(nr));
  asm("v_fma_mix_f32 %0, %1, %2, %0 op_sel:[1,0,0] op_sel_hi:[1,0,0]"
      : "+v"(acc[1]) : "v"(q.x), "v"(nr));
  asm("v_fma_mix_f32 %0, %1, %2, %0 op_sel:[0,0,0] op_sel_hi:[1,0,0]"
      : "+v"(acc[2]) : "v"(q.y), "v"(nr));
  asm("v_fma_mix_f32 %0, %1, %2, %0 op_sel:[1,0,0] op_sel_hi:[1,0,0]"
      : "+v"(acc[3]) : "v"(q.y), "v"(nr));
  asm("v_fma_mix_f32 %0, %1, %2, %0 op_sel:[0,0,0] op_sel_hi:[1,0,0]"
      : "+v"(acc[4]) : "v"(q.z), "v"(nr));
  asm("v_fma_mix_f32 %0, %1, %2, %0 op_sel:[1,0,0] op_sel_hi:[1,0,0]"
      : "+v"(acc[5]) : "v"(q.z), "v"(nr));
  asm("v_fma_mix_f32 %0, %1, %2, %0 op_sel:[0,0,0] op_sel_hi:[1,0,0]"
      : "+v"(acc[6]) : "v"(q.w), "v"(nr));
  asm("v_fma_mix_f32 %0, %1, %2, %0 op_sel:[1,0,0] op_sel_hi:[1,0,0]"
      : "+v"(acc[7]) : "v"(q.w), "v"(nr));
}

// ---------------------------------------------------------------------------
// W [128][128] fp32 -> bf16 in MFMA B-fragment order.
__global__ __launch_bounds__(256) void cvtw_kernel(
    const float* __restrict__ w, unsigned short* __restrict__ wfrag) {
  const int i = blockIdx.x * 256 + threadIdx.x;  // 16384 elems, 64 blocks
  const int c = i >> 7, k = i & 127;
  const int pos = ((((c >> 4) << 2) + (k >> 5)) * 64 +
                   (((k >> 3) & 3) << 4) + (c & 15)) * 8 + (k & 7);
  wfrag[pos] = f2bf(w[i]);
}

// ---------------------------------------------------------------------------
// MFMA gemm: g[n][c] = sum_k f[n][k] w[c][k], output plain row-major f16.
__global__ __launch_bounds__(256) void gemm_kernel(
    const float* __restrict__ f, const unsigned short* __restrict__ wfrag,
    unsigned short* __restrict__ gh) {
  const int wv = blockIdx.x * 4 + (threadIdx.x >> 6);
  if (wv >= NTILE) return;
  const int lane = threadIdx.x & 63;
  const int mrow = lane & 15;
  const int q = lane >> 4;
  const long node = (long)wv * 16 + mrow;
  const float* fr = f + node * D + q * 8;

  bf16x8 a[4];
#pragma unroll
  for (int ks = 0; ks < 4; ++ks) {
    const float4 lo = *(const float4*)(fr + ks * 32);
    const float4 hi = *(const float4*)(fr + ks * 32 + 4);
    union { bf16x8 v; unsigned short u[8]; } pa;
    pa.u[0] = f2bf(lo.x); pa.u[1] = f2bf(lo.y);
    pa.u[2] = f2bf(lo.z); pa.u[3] = f2bf(lo.w);
    pa.u[4] = f2bf(hi.x); pa.u[5] = f2bf(hi.y);
    pa.u[6] = f2bf(hi.z); pa.u[7] = f2bf(hi.w);
    a[ks] = pa.v;
  }

  const long nbase = (long)wv * 16 + (q << 2);
#pragma unroll
  for (int tc = 0; tc < 8; ++tc) {
    f32x4 acc = {0.f, 0.f, 0.f, 0.f};
#pragma unroll
    for (int ks = 0; ks < 4; ++ks) {
      const bf16x8 b =
          *(const bf16x8*)(wfrag + (((tc << 2) + ks) * 64 + lane) * 8);
      acc = __builtin_amdgcn_mfma_f32_16x16x32_bf16(a[ks], b, acc, 0, 0, 0);
    }
    const int c = (tc << 4) + mrow;
#pragma unroll
    for (int r = 0; r < 4; ++r) {
      union { _Float16 h; unsigned short u; } cv;
      cv.h = (_Float16)acc[r];  // v_cvt_f16_f32, RTNE
      gh[(nbase + r) * D + c] = cv.u;
    }
  }
}

// ---------------------------------------------------------------------------
// Per-node degree histogram: 3.2M global atomics into 400KB (L2-resident).
// dst read as int4 (coalesced 16B/lane). 800,000 int4s = 3125 blocks x 256.
__global__ __launch_bounds__(256) void histn_kernel(const int* __restrict__ dst,
                                                    int* __restrict__ cur) {
  const int i = blockIdx.x * 256 + threadIdx.x;
  const int4 d = ((const int4*)dst)[i];
  atomicAdd(&cur[d.x], 1);
  atomicAdd(&cur[d.y], 1);
  atomicAdd(&cur[d.z], 1);
  atomicAdd(&cur[d.w], 1);
}

// ---------------------------------------------------------------------------
// Single-block exclusive scan of 100K counts (in cur) -> starts, written to
// BOTH row_ptr (persistent) and cur (consumed by place_kernel's atomics).
// 16 waves x 6400 elems each; per-tile (256 elems, int4/lane) coalesced
// loads + wave shfl scan; two-phase for cross-wave offsets.
__global__ __launch_bounds__(1024) void scan100k_kernel(
    int* __restrict__ cur, int* __restrict__ row_ptr) {
  __shared__ int wsum[16];
  const int t = threadIdx.x;
  const int w = t >> 6, lane = t & 63;
  const int wbeg = w * 6400;

  // phase 1: wave total
  int tot = 0;
  for (int base = wbeg; base < wbeg + 6400; base += 256) {
    const int idx = base + lane * 4;
    int4 v = {0, 0, 0, 0};
    if (idx + 3 < NN) v = *(const int4*)(cur + idx);
    else {
      if (idx + 0 < NN) v.x = cur[idx + 0];
      if (idx + 1 < NN) v.y = cur[idx + 1];
      if (idx + 2 < NN) v.z = cur[idx + 2];
      if (idx + 3 < NN) v.w = cur[idx + 3];
    }
    tot += v.x + v.y + v.z + v.w;
  }
#pragma unroll
  for (int off = 1; off < 64; off <<= 1) tot += __shfl_xor(tot, off, 64);
  if (lane == 0) wsum[w] = tot;
  __syncthreads();
  if (w == 0 && lane < 16) {
    const int v = wsum[lane];
    int inc = v;
#pragma unroll
    for (int off = 1; off < 16; off <<= 1) {
      int x = __shfl_up(inc, off, 64);
      if (lane >= off) inc += x;
    }
    wsum[lane] = inc - v;  // exclusive
  }
  __syncthreads();

  // phase 2: per-tile wave scan with running offset
  int run = wsum[w];
  for (int base = wbeg; base < wbeg + 6400; base += 256) {
    const int idx = base + lane * 4;
    int4 v = {0, 0, 0, 0};
    const bool full = (idx + 3 < NN);
    if (full) v = *(const int4*)(cur + idx);
    else {
      if (idx + 0 < NN) v.x = cur[idx + 0];
      if (idx + 1 < NN) v.y = cur[idx + 1];
      if (idx + 2 < NN) v.z = cur[idx + 2];
      if (idx + 3 < NN) v.w = cur[idx + 3];
    }
    const int s = v.x + v.y + v.z + v.w;
    int inc = s;
#pragma unroll
    for (int off = 1; off < 64; off <<= 1) {
      int x = __shfl_up(inc, off, 64);
      if (lane >= off) inc += x;
    }
    const int ex = run + inc - s;
    int4 o;
    o.x = ex;
    o.y = ex + v.x;
    o.z = ex + v.x + v.y;
    o.w = ex + v.x + v.y + v.z;
    if (full) {
      *(int4*)(cur + idx) = o;
      *(int4*)(row_ptr + idx) = o;
    } else {
      if (idx + 0 < NN) { cur[idx + 0] = o.x; row_ptr[idx + 0] = o.x; }
      if (idx + 1 < NN) { cur[idx + 1] = o.y; row_ptr[idx + 1] = o.y; }
      if (idx + 2 < NN) { cur[idx + 2] = o.z; row_ptr[idx + 2] = o.z; }
      if (idx + 3 < NN) { cur[idx + 3] = o.w; row_ptr[idx + 3] = o.w; }
    }
    run += __shfl(inc, 63, 64);
  }
  if (t == 0) row_ptr[NN] = NE;
}

// ---------------------------------------------------------------------------
// Direct placement: r = cur[dst]++ (global atomic), bufB[r] = {src, norm}.
// Edges land grouped by dst at final position; order within a node is
// arbitrary (pull is order-agnostic). 3125 blocks x 256, int4/float4 reads.
__global__ __launch_bounds__(256) void place_kernel(
    const int* __restrict__ src, const int* __restrict__ dst,
    const float* __restrict__ norm, int* __restrict__ cur,
    int2* __restrict__ bufB) {
  const int i = blockIdx.x * 256 + threadIdx.x;
  const int4 s = ((const int4*)src)[i];
  const int4 d = ((const int4*)dst)[i];
  const float4 nr = ((const float4*)norm)[i];
  int2 m;
  int r;
  r = atomicAdd(&cur[d.x], 1); m.x = s.x; m.y = __float_as_int(nr.x); bufB[r] = m;
  r = atomicAdd(&cur[d.y], 1); m.x = s.y; m.y = __float_as_int(nr.y); bufB[r] = m;
  r = atomicAdd(&cur[d.z], 1); m.x = s.z; m.y = __float_as_int(nr.z); bufB[r] = m;
  r = atomicAdd(&cur[d.w], 1); m.x = s.w; m.y = __float_as_int(nr.w); bufB[r] = m;
}

// ---------------------------------------------------------------------------
// Pull (R8, unchanged): one wave per node; 16 lanes per edge; dwordx4 f16
// gathers; depth-2 software pipeline; fma_mix consumes f16 halves directly.
__global__ __launch_bounds__(256) void pull_kernel(
    const unsigned short* __restrict__ gh, const int* __restrict__ row_ptr,
    const int2* __restrict__ bufB, const float* __restrict__ bias,
    float* __restrict__ out) {
  const int n = blockIdx.x * 4 + (threadIdx.x >> 6);
  if (n >= NN) return;
  const int lane = threadIdx.x & 63;
  const int s = lane & 15;   // sublane: channels s*8 .. s*8+7
  const int g = lane >> 4;   // edge group
  const int beg = row_ptr[n];
  const int end = row_ptr[n + 1];

  float acc[8] = {0.f, 0.f, 0.f, 0.f, 0.f, 0.f, 0.f, 0.f};

  if (beg < end) {
    const char* gbase = (const char*)gh;
    const unsigned soff = (unsigned)(s << 4);  // byte offset within row
    const int last = end - 1;
    int e0 = beg;
    int2 mA0 = bufB[min(e0 + g, last)];
    int2 mB0 = bufB[min(e0 + 4 + g, last)];
    uint4 qA0 = *(const uint4*)(gbase + (((unsigned)mA0.x << 8) + soff));
    uint4 qB0 = *(const uint4*)(gbase + (((unsigned)mB0.x << 8) + soff));
    int2 mA1 = bufB[min(e0 + 8 + g, last)];
    int2 mB1 = bufB[min(e0 + 12 + g, last)];
    while (e0 + 8 < end) {
      const int2 mA2 = bufB[min(e0 + 16 + g, last)];
      const int2 mB2 = bufB[min(e0 + 20 + g, last)];
      const uint4 qA1 =
          *(const uint4*)(gbase + (((unsigned)mA1.x << 8) + soff));
      const uint4 qB1 =
          *(const uint4*)(gbase + (((unsigned)mB1.x << 8) + soff));
      fmix8(acc, qA0, __int_as_float(mA0.y));
      fmix8(acc, qB0, __int_as_float(mB0.y));
      mA0 = mA1; mB0 = mB1;
      mA1 = mA2; mB1 = mB2;
      qA0 = qA1; qB0 = qB1;
      e0 += 8;
    }
    const float nrA = (e0 + g < end) ? __int_as_float(mA0.y) : 0.f;
    const float nrB = (e0 + 4 + g < end) ? __int_as_float(mB0.y) : 0.f;
    fmix8(acc, qA0, nrA);
    fmix8(acc, qB0, nrB);
  }

#pragma unroll
  for (int k = 0; k < 8; ++k) {
    acc[k] += __shfl_xor(acc[k], 16, 64);
    acc[k] += __shfl_xor(acc[k], 32, 64);
  }
  if (g < 2) {
    const bool hi = (g == 1);
    const float r0 = hi ? acc[4] : acc[0];
    const float r1 = hi ? acc[5] : acc[1];
    const float r2 = hi ? acc[6] : acc[2];
    const float r3 = hi ? acc[7] : acc[3];
    const int cb = (s << 3) + (g << 2);
    const float4 b4 = *(const float4*)(bias + cb);
    float4 r;
    r.x = r0 + b4.x;
    r.y = r1 + b4.y;
    r.z = r2 + b4.z;
    r.w = r3 + b4.w;
    *(float4*)(out + (long)n * D + cb) = r;
  }
}

// ---------------------------------------------------------------------------
// Fallback (ws too small): R1 path.
__global__ __launch_bounds__(256) void gemm_f32_kernel(
    const float* __restrict__ f, const float* __restrict__ w,
    float* __restrict__ g) {
  __shared__ float wlds[D * D];
  const int t = threadIdx.x;
  for (int i = t; i < D * D; i += 256) {
    int c = i >> 7, k = i & 127;
    wlds[(c << 7) + (k ^ (c & 31))] = w[i];
  }
  __syncthreads();
  const int c = t & 127;
  const int cx = c & 31;
  const int cbase = c << 7;
  const int jbase = __builtin_amdgcn_readfirstlane((t >> 7) << 3);
  const long nb = (long)blockIdx.x * 16 + jbase;
  const float* __restrict__ frow = f + nb * D;
  float acc[8] = {0.f, 0.f, 0.f, 0.f, 0.f, 0.f, 0.f, 0.f};
#pragma unroll 4
  for (int k = 0; k < D; ++k) {
    float wv = wlds[cbase + (k ^ cx)];
#pragma unroll
    for (int j = 0; j < 8; ++j) acc[j] += frow[j * D + k] * wv;
  }
#pragma unroll
  for (int j = 0; j < 8; ++j) g[(nb + j) * D + c] = acc[j];
}

__global__ __launch_bounds__(256) void init_kernel(
    const float* __restrict__ bias, float4* __restrict__ out) {
  const int i = blockIdx.x * 256 + threadIdx.x;
  const float4* b4 = (const float4*)bias;
  out[i] = b4[i & 31];
}

__global__ __launch_bounds__(256) void scatter_kernel(
    const float* __restrict__ g, const float* __restrict__ norm,
    const int* __restrict__ src, const int* __restrict__ dst,
    float* __restrict__ out) {
  const long tid = (long)blockIdx.x * 256 + threadIdx.x;
  const int e = (int)(tid >> 5);
  if (e >= NE) return;
  const int ch = (int)(tid & 31) << 2;
  const int s = src[e];
  const int d = dst[e];
  const float nr = norm[e];
  const float4 gv = *(const float4*)(g + (long)s * D + ch);
  float* op = out + (long)d * D + ch;
  unsafeAtomicAdd(op + 0, nr * gv.x);
  unsafeAtomicAdd(op + 1, nr * gv.y);
  unsafeAtomicAdd(op + 2, nr * gv.z);
  unsafeAtomicAdd(op + 3, nr * gv.w);
}

// ---------------------------------------------------------------------------
extern "C" void kernel_launch(void* const* d_in, const int* in_sizes, int n_in,
                              void* d_out, int out_size, void* d_ws,
                              size_t ws_size, hipStream_t stream) {
  const float* features = (const float*)d_in[0];
  const float* norm     = (const float*)d_in[1];
  const int*   src      = (const int*)d_in[2];
  const int*   dst      = (const int*)d_in[3];
  const float* weight   = (const float*)d_in[4];
  const float* bias     = (const float*)d_in[5];
  float* out = (float*)d_out;

  char* ws = (char*)d_ws;
  unsigned short* gh    = (unsigned short*)ws;   // [0, 25.6M)  f16 g-matrix
  int2* bufB    = (int2*)(ws + 25600000);        // [25.6M, 51.2M)
  int*  row_ptr = (int*)(ws + 51200000);         // 400,004 B (16-aligned)
  int*  cur     = (int*)(ws + 51600016);         // 400,000 B (16-aligned)
  unsigned short* wfrag = (unsigned short*)(ws + 52000016);  // 32,768 B
  const size_t need = 52032784;                  // ws >= 77,602,176 proven (R2)

  if (ws_size >= need) {
    hipMemsetAsync(cur, 0, NN * sizeof(int), stream);
    hipLaunchKernelGGL(cvtw_kernel, dim3(64), dim3(256), 0, stream,
                       weight, wfrag);
    hipLaunchKernelGGL(gemm_kernel, dim3((NTILE + 3) / 4), dim3(256), 0,
                       stream, features, wfrag, gh);
    hipLaunchKernelGGL(histn_kernel, dim3(NE / 1024), dim3(256), 0, stream,
                       dst, cur);
    hipLaunchKernelGGL(scan100k_kernel, dim3(1), dim3(1024), 0, stream,
                       cur, row_ptr);
    hipLaunchKernelGGL(place_kernel, dim3(NE / 1024), dim3(256), 0, stream,
                       src, dst, norm, cur, bufB);
    hipLaunchKernelGGL(pull_kernel, dim3((NN + 3) / 4), dim3(256), 0, stream,
                       gh, row_ptr, bufB, bias, out);
  } else {
    float* g = (float*)ws;
    hipLaunchKernelGGL(gemm_f32_kernel, dim3(NN / 16), dim3(256), 0, stream,
                       features, weight, g);
    hipLaunchKernelGGL(init_kernel, dim3((NN * D / 4) / 256), dim3(256), 0,
                       stream, bias, (float4*)out);
    hipLaunchKernelGGL(scatter_kernel, dim3((long)NE * 32 / 256), dim3(256), 0,
                       stream, g, norm, src, dst, out);
  }
}

// Round 5
// 340.593 us; speedup vs baseline: 1.8466x; 1.8466x over previous
//
#include <hip/hip_runtime.h>

// SparseGCNConv: out = segment_sum(norm * f[src], dst, N) @ W^T + bias
// R10: revert R9's direct placement (8x write amp, 250us). Two-level bucket
// sort restored with: 256-node buckets (391) for denser bin write runs
// (84B -> 335B), int4-vectorized hist/bin edge reads, hist fused into the
// gemm launch (independent block range), 4x-replicated LDS counters, fat
// sort blocks with in-block scan. pull (fabric-bound 106us) unchanged.

#define NN    100000
#define NE    3200000
#define D     128
#define NBKT  391    // ceil(NN/256); bucket b = dst >> 8
#define NI4   800000 // NE/4 int4 elements
#define NTILE 6250   // NN/16 node tiles (exact)
#define GB    1563   // gemm blocks in fused gemmhist launch
#define HB    782    // hist blocks  (782*1024 int4 >= 800000)

typedef __attribute__((ext_vector_type(8))) short bf16x8;
typedef __attribute__((ext_vector_type(4))) float f32x4;

static __device__ __forceinline__ unsigned short f2bf(float x) {
  unsigned u = __float_as_uint(x);
  u += 0x7FFFu + ((u >> 16) & 1u);  // RTNE
  return (unsigned short)(u >> 16);
}

// 8 channels of one gathered f16 row-slice, scaled by nr, into f32 accs.
static __device__ __forceinline__ void fmix8(float* acc, uint4 q, float nr) {
  asm("v_fma_mix_f32 %0, %1, %2, %0 op_sel:[0,0,0] op_sel_hi:[1,0,0]"
      : "+v"(acc[0]) : "v"(q.x), "v"(nr));
  asm("v_fma_mix_f32 %0, %1, %2, %0 op_sel:[1,0,0] op_sel_hi:[1,0,0]"
      : "+v"(acc[1]) : "v"(q.x), "v"(nr));
  asm("v_fma_mix_f32 %0, %1, %2, %0 op_sel:[0,0,0] op_sel_hi:[1,0,0]"
      : "+v"(acc[2]) : "v"(q.y), "v"(nr));
  asm("v_fma_mix_f32 %0, %1, %2, %0 op_sel:[1,0,0] op_sel_hi:[1,0,0]"
      : "+v"(acc[3]) : "v"(q.y), "v"(nr));
  asm("v_fma_mix_f32 %0, %1, %2, %0 op_sel:[0,0,0] op_sel_hi:[1,0,0]"
      : "+v"(acc[4]) : "v"(q.z), "v"(nr));
  asm("v_fma_mix_f32 %0, %1, %2, %0 op_sel:[1,0,0] op_sel_hi:[1,0,0]"
      : "+v"(acc[5]) : "v"(q.z), "v"(nr));
  asm("v_fma_mix_f32 %0, %1, %2, %0 op_sel:[0,0,0] op_sel_hi:[1,0,0]"
      : "+v"(acc[6]) : "v"(q.w), "v"(nr));
  asm("v_fma_mix_f32 %0, %1, %2, %0 op_sel:[1,0,0] op_sel_hi:[1,0,0]"
      : "+v"(acc[7]) : "v"(q.w), "v"(nr));
}

// ---------------------------------------------------------------------------
// W [128][128] fp32 -> bf16 in MFMA B-fragment order.
__global__ __launch_bounds__(256) void cvtw_kernel(
    const float* __restrict__ w, unsigned short* __restrict__ wfrag) {
  const int i = blockIdx.x * 256 + threadIdx.x;  // 16384 elems, 64 blocks
  const int c = i >> 7, k = i & 127;
  const int pos = ((((c >> 4) << 2) + (k >> 5)) * 64 +
                   (((k >> 3) & 3) << 4) + (c & 15)) * 8 + (k & 7);
  wfrag[pos] = f2bf(w[i]);
}

// ---------------------------------------------------------------------------
// Fused: blocks [0,GB) = MFMA gemm (g = f @ W^T, f16 out); blocks [GB,GB+HB)
// = bucket histogram (int4 dst reads, 4x-replicated LDS counters).
// The two halves touch disjoint data; hist hides under gemm's memory time.
__global__ __launch_bounds__(256) void gemmhist_kernel(
    const float* __restrict__ f, const unsigned short* __restrict__ wfrag,
    unsigned short* __restrict__ gh, const int* __restrict__ dst,
    int* __restrict__ gcnt) {
  __shared__ int h[4][NBKT];
  if (blockIdx.x >= GB) {
    const int t = threadIdx.x;
    for (int i = t; i < 4 * NBKT; i += 256) ((int*)h)[i] = 0;
    __syncthreads();
    const int i4base = (blockIdx.x - GB) * 1024;
    const int rep = t & 3;
#pragma unroll
    for (int i = 0; i < 4; ++i) {
      const int idx = i4base + i * 256 + t;
      if (idx < NI4) {
        const int4 d = ((const int4*)dst)[idx];
        atomicAdd(&h[rep][d.x >> 8], 1);
        atomicAdd(&h[rep][d.y >> 8], 1);
        atomicAdd(&h[rep][d.z >> 8], 1);
        atomicAdd(&h[rep][d.w >> 8], 1);
      }
    }
    __syncthreads();
    for (int b = t; b < NBKT; b += 256) {
      const int v = h[0][b] + h[1][b] + h[2][b] + h[3][b];
      if (v) atomicAdd(&gcnt[b], v);
    }
    return;
  }

  const int wv = blockIdx.x * 4 + (threadIdx.x >> 6);
  if (wv >= NTILE) return;
  const int lane = threadIdx.x & 63;
  const int mrow = lane & 15;
  const int q = lane >> 4;
  const long node = (long)wv * 16 + mrow;
  const float* fr = f + node * D + q * 8;

  bf16x8 a[4];
#pragma unroll
  for (int ks = 0; ks < 4; ++ks) {
    const float4 lo = *(const float4*)(fr + ks * 32);
    const float4 hi = *(const float4*)(fr + ks * 32 + 4);
    union { bf16x8 v; unsigned short u[8]; } pa;
    pa.u[0] = f2bf(lo.x); pa.u[1] = f2bf(lo.y);
    pa.u[2] = f2bf(lo.z); pa.u[3] = f2bf(lo.w);
    pa.u[4] = f2bf(hi.x); pa.u[5] = f2bf(hi.y);
    pa.u[6] = f2bf(hi.z); pa.u[7] = f2bf(hi.w);
    a[ks] = pa.v;
  }

  const long nbase = (long)wv * 16 + (q << 2);
#pragma unroll
  for (int tc = 0; tc < 8; ++tc) {
    f32x4 acc = {0.f, 0.f, 0.f, 0.f};
#pragma unroll
    for (int ks = 0; ks < 4; ++ks) {
      const bf16x8 b =
          *(const bf16x8*)(wfrag + (((tc << 2) + ks) * 64 + lane) * 8);
      acc = __builtin_amdgcn_mfma_f32_16x16x32_bf16(a[ks], b, acc, 0, 0, 0);
    }
    const int c = (tc << 4) + mrow;
#pragma unroll
    for (int r = 0; r < 4; ++r) {
      union { _Float16 hh; unsigned short u; } cv;
      cv.hh = (_Float16)acc[r];  // v_cvt_f16_f32, RTNE
      gh[(nbase + r) * D + c] = cv.u;
    }
  }
}

// ---------------------------------------------------------------------------
// Exclusive scan of NBKT (=391) bucket counts -> bstart (persistent) and
// cur_b (consumed by bin's reservations). Proven R5 shape (<=2048 elems).
__global__ __launch_bounds__(1024) void scan_kernel(const int* __restrict__ gcnt,
                                                    int* __restrict__ bstart,
                                                    int* __restrict__ cur_b,
                                                    int* __restrict__ row_ptr) {
  __shared__ int s[2048];
  const int t = threadIdx.x;
  s[t] = (t < NBKT) ? gcnt[t] : 0;
  s[t + 1024] = 0;
  __syncthreads();
  if (t < 64) {
    int part = 0;
#pragma unroll
    for (int i = 0; i < 32; ++i) part += s[(t << 5) + i];
    int inc = part;
#pragma unroll
    for (int off = 1; off < 64; off <<= 1) {
      int x = __shfl_up(inc, off, 64);
      if (t >= off) inc += x;
    }
    int run = inc - part;
#pragma unroll
    for (int i = 0; i < 32; ++i) {
      int idx = (t << 5) + i;
      int v = s[idx];
      s[idx] = run;
      run += v;
    }
  }
  __syncthreads();
  if (t < NBKT) { bstart[t] = s[t]; cur_b[t] = s[t]; }
  if (t == 0) { bstart[NBKT] = NE; row_ptr[NN] = NE; }
}

// ---------------------------------------------------------------------------
// Bin edges into 256-node buckets. int4/float4 reads (4 edges/thread/iter);
// per-block bucket runs avg 16384/391 ~= 42 edges = 335B (write amp ~1.2).
// Pack: m.x = src | ((dst & 255) << 17)  (src < 2^17).
__global__ __launch_bounds__(1024) void bin_kernel(
    const int* __restrict__ src, const int* __restrict__ dst,
    const float* __restrict__ norm, int* __restrict__ cur_b,
    int2* __restrict__ bufA) {
  __shared__ int bcnt[4][NBKT];
  __shared__ int bbase[NBKT];
  __shared__ int brank[NBKT];
  const int t = threadIdx.x;
  for (int i = t; i < 4 * NBKT; i += 1024) ((int*)bcnt)[i] = 0;
  if (t < NBKT) brank[t] = 0;
  __syncthreads();
  const int i4base = blockIdx.x * 4096;
  const int rep = t & 3;
#pragma unroll
  for (int i = 0; i < 4; ++i) {
    const int idx = i4base + i * 1024 + t;
    if (idx < NI4) {
      const int4 d = ((const int4*)dst)[idx];
      atomicAdd(&bcnt[rep][d.x >> 8], 1);
      atomicAdd(&bcnt[rep][d.y >> 8], 1);
      atomicAdd(&bcnt[rep][d.z >> 8], 1);
      atomicAdd(&bcnt[rep][d.w >> 8], 1);
    }
  }
  __syncthreads();
  if (t < NBKT) {
    const int c = bcnt[0][t] + bcnt[1][t] + bcnt[2][t] + bcnt[3][t];
    if (c) bbase[t] = atomicAdd(&cur_b[t], c);
  }
  __syncthreads();
#pragma unroll
  for (int i = 0; i < 4; ++i) {
    const int idx = i4base + i * 1024 + t;
    if (idx < NI4) {
      const int4 s = ((const int4*)src)[idx];
      const int4 d = ((const int4*)dst)[idx];
      const float4 nr = ((const float4*)norm)[idx];
      int bb, r; int2 m;
      bb = d.x >> 8; r = atomicAdd(&brank[bb], 1);
      m.x = s.x | ((d.x & 255) << 17); m.y = __float_as_int(nr.x);
      bufA[bbase[bb] + r] = m;
      bb = d.y >> 8; r = atomicAdd(&brank[bb], 1);
      m.x = s.y | ((d.y & 255) << 17); m.y = __float_as_int(nr.y);
      bufA[bbase[bb] + r] = m;
      bb = d.z >> 8; r = atomicAdd(&brank[bb], 1);
      m.x = s.z | ((d.z & 255) << 17); m.y = __float_as_int(nr.z);
      bufA[bbase[bb] + r] = m;
      bb = d.w >> 8; r = atomicAdd(&brank[bb], 1);
      m.x = s.w | ((d.w & 255) << 17); m.y = __float_as_int(nr.w);
      bufA[bbase[bb] + r] = m;
    }
  }
}

// ---------------------------------------------------------------------------
// Per-bucket counting sort by local node (256 locals, 512 threads/block).
__global__ __launch_bounds__(512) void sort_kernel(
    const int2* __restrict__ bufA, const int* __restrict__ bstart,
    int2* __restrict__ bufB, int* __restrict__ row_ptr) {
  __shared__ int lcnt[256];
  __shared__ int lbase[256];
  __shared__ int wtot[4];
  const int b = blockIdx.x;
  const int t = threadIdx.x;
  const int beg = bstart[b];
  const int end = bstart[b + 1];
  if (t < 256) lcnt[t] = 0;
  __syncthreads();
  for (int e = beg + t; e < end; e += 512)
    atomicAdd(&lcnt[(bufA[e].x >> 17) & 255], 1);
  __syncthreads();
  int v = 0, inc = 0;
  const int lane = t & 63;
  if (t < 256) {
    v = lcnt[t];
    inc = v;
#pragma unroll
    for (int off = 1; off < 64; off <<= 1) {
      int x = __shfl_up(inc, off, 64);
      if (lane >= off) inc += x;
    }
    if (lane == 63) wtot[t >> 6] = inc;
  }
  __syncthreads();
  if (t == 0) {
    int run = 0;
#pragma unroll
    for (int i = 0; i < 4; ++i) { int x = wtot[i]; wtot[i] = run; run += x; }
  }
  __syncthreads();
  if (t < 256) {
    const int ex = wtot[t >> 6] + inc - v;
    lbase[t] = ex;
    const int n = (b << 8) + t;
    if (n < NN) row_ptr[n] = beg + ex;
    lcnt[t] = 0;
  }
  __syncthreads();
  for (int e = beg + t; e < end; e += 512) {
    const int2 m = bufA[e];
    const int nl = (m.x >> 17) & 255;
    const int r = atomicAdd(&lcnt[nl], 1);
    int2 o;
    o.x = m.x & 0x1FFFF;
    o.y = m.y;
    bufB[beg + lbase[nl] + r] = o;
  }
}

// ---------------------------------------------------------------------------
// Pull (R8, unchanged/proven): one wave per node; 16 lanes per edge; dwordx4
// f16 gathers; depth-2 software pipeline; fma_mix consumes f16 halves.
__global__ __launch_bounds__(256) void pull_kernel(
    const unsigned short* __restrict__ gh, const int* __restrict__ row_ptr,
    const int2* __restrict__ bufB, const float* __restrict__ bias,
    float* __restrict__ out) {
  const int n = blockIdx.x * 4 + (threadIdx.x >> 6);
  if (n >= NN) return;
  const int lane = threadIdx.x & 63;
  const int s = lane & 15;   // sublane: channels s*8 .. s*8+7
  const int g = lane >> 4;   // edge group
  const int beg = row_ptr[n];
  const int end = row_ptr[n + 1];

  float acc[8] = {0.f, 0.f, 0.f, 0.f, 0.f, 0.f, 0.f, 0.f};

  if (beg < end) {
    const char* gbase = (const char*)gh;
    const unsigned soff = (unsigned)(s << 4);  // byte offset within row
    const int last = end - 1;
    int e0 = beg;
    int2 mA0 = bufB[min(e0 + g, last)];
    int2 mB0 = bufB[min(e0 + 4 + g, last)];
    uint4 qA0 = *(const uint4*)(gbase + (((unsigned)mA0.x << 8) + soff));
    uint4 qB0 = *(const uint4*)(gbase + (((unsigned)mB0.x << 8) + soff));
    int2 mA1 = bufB[min(e0 + 8 + g, last)];
    int2 mB1 = bufB[min(e0 + 12 + g, last)];
    while (e0 + 8 < end) {
      const int2 mA2 = bufB[min(e0 + 16 + g, last)];
      const int2 mB2 = bufB[min(e0 + 20 + g, last)];
      const uint4 qA1 =
          *(const uint4*)(gbase + (((unsigned)mA1.x << 8) + soff));
      const uint4 qB1 =
          *(const uint4*)(gbase + (((unsigned)mB1.x << 8) + soff));
      fmix8(acc, qA0, __int_as_float(mA0.y));
      fmix8(acc, qB0, __int_as_float(mB0.y));
      mA0 = mA1; mB0 = mB1;
      mA1 = mA2; mB1 = mB2;
      qA0 = qA1; qB0 = qB1;
      e0 += 8;
    }
    const float nrA = (e0 + g < end) ? __int_as_float(mA0.y) : 0.f;
    const float nrB = (e0 + 4 + g < end) ? __int_as_float(mB0.y) : 0.f;
    fmix8(acc, qA0, nrA);
    fmix8(acc, qB0, nrB);
  }

#pragma unroll
  for (int k = 0; k < 8; ++k) {
    acc[k] += __shfl_xor(acc[k], 16, 64);
    acc[k] += __shfl_xor(acc[k], 32, 64);
  }
  if (g < 2) {
    const bool hi = (g == 1);
    const float r0 = hi ? acc[4] : acc[0];
    const float r1 = hi ? acc[5] : acc[1];
    const float r2 = hi ? acc[6] : acc[2];
    const float r3 = hi ? acc[7] : acc[3];
    const int cb = (s << 3) + (g << 2);
    const float4 b4 = *(const float4*)(bias + cb);
    float4 r;
    r.x = r0 + b4.x;
    r.y = r1 + b4.y;
    r.z = r2 + b4.z;
    r.w = r3 + b4.w;
    *(float4*)(out + (long)n * D + cb) = r;
  }
}

// ---------------------------------------------------------------------------
// Fallback (ws too small): R1 path.
__global__ __launch_bounds__(256) void gemm_f32_kernel(
    const float* __restrict__ f, const float* __restrict__ w,
    float* __restrict__ g) {
  __shared__ float wlds[D * D];
  const int t = threadIdx.x;
  for (int i = t; i < D * D; i += 256) {
    int c = i >> 7, k = i & 127;
    wlds[(c << 7) + (k ^ (c & 31))] = w[i];
  }
  __syncthreads();
  const int c = t & 127;
  const int cx = c & 31;
  const int cbase = c << 7;
  const int jbase = __builtin_amdgcn_readfirstlane((t >> 7) << 3);
  const long nb = (long)blockIdx.x * 16 + jbase;
  const float* __restrict__ frow = f + nb * D;
  float acc[8] = {0.f, 0.f, 0.f, 0.f, 0.f, 0.f, 0.f, 0.f};
#pragma unroll 4
  for (int k = 0; k < D; ++k) {
    float wv = wlds[cbase + (k ^ cx)];
#pragma unroll
    for (int j = 0; j < 8; ++j) acc[j] += frow[j * D + k] * wv;
  }
#pragma unroll
  for (int j = 0; j < 8; ++j) g[(nb + j) * D + c] = acc[j];
}

__global__ __launch_bounds__(256) void init_kernel(
    const float* __restrict__ bias, float4* __restrict__ out) {
  const int i = blockIdx.x * 256 + threadIdx.x;
  const float4* b4 = (const float4*)bias;
  out[i] = b4[i & 31];
}

__global__ __launch_bounds__(256) void scatter_kernel(
    const float* __restrict__ g, const float* __restrict__ norm,
    const int* __restrict__ src, const int* __restrict__ dst,
    float* __restrict__ out) {
  const long tid = (long)blockIdx.x * 256 + threadIdx.x;
  const int e = (int)(tid >> 5);
  if (e >= NE) return;
  const int ch = (int)(tid & 31) << 2;
  const int s = src[e];
  const int d = dst[e];
  const float nr = norm[e];
  const float4 gv = *(const float4*)(g + (long)s * D + ch);
  float* op = out + (long)d * D + ch;
  unsafeAtomicAdd(op + 0, nr * gv.x);
  unsafeAtomicAdd(op + 1, nr * gv.y);
  unsafeAtomicAdd(op + 2, nr * gv.z);
  unsafeAtomicAdd(op + 3, nr * gv.w);
}

// ---------------------------------------------------------------------------
extern "C" void kernel_launch(void* const* d_in, const int* in_sizes, int n_in,
                              void* d_out, int out_size, void* d_ws,
                              size_t ws_size, hipStream_t stream) {
  const float* features = (const float*)d_in[0];
  const float* norm     = (const float*)d_in[1];
  const int*   src      = (const int*)d_in[2];
  const int*   dst      = (const int*)d_in[3];
  const float* weight   = (const float*)d_in[4];
  const float* bias     = (const float*)d_in[5];
  float* out = (float*)d_out;

  char* ws = (char*)d_ws;
  unsigned short* gh    = (unsigned short*)ws;   // [0, 25.6M)  f16 g-matrix
  int2* bufA    = (int2*)(ws + 25600000);        // [25.6M, 51.2M)
  int2* bufB    = (int2*)(ws + 51200000);        // [51.2M, 76.8M)
  int*  row_ptr = (int*)(ws + 76800000);         // 400,004 B
  int*  gcnt    = (int*)(ws + 77200016);         // 1,564 B
  int*  bstart  = (int*)(ws + 77201584);         // 1,568 B
  int*  cur_b   = (int*)(ws + 77203152);         // 1,564 B
  unsigned short* wfrag = (unsigned short*)(ws + 77204720);  // 32,768 B
  const size_t need = 77237488;                  // ws >= 77,602,176 proven (R2)

  if (ws_size >= need) {
    hipMemsetAsync(gcnt, 0, NBKT * sizeof(int), stream);
    hipLaunchKernelGGL(cvtw_kernel, dim3(64), dim3(256), 0, stream,
                       weight, wfrag);
    hipLaunchKernelGGL(gemmhist_kernel, dim3(GB + HB), dim3(256), 0, stream,
                       features, wfrag, gh, dst, gcnt);
    hipLaunchKernelGGL(scan_kernel, dim3(1), dim3(1024), 0, stream,
                       gcnt, bstart, cur_b, row_ptr);
    hipLaunchKernelGGL(bin_kernel, dim3((NI4 + 4095) / 4096), dim3(1024), 0,
                       stream, src, dst, norm, cur_b, bufA);
    hipLaunchKernelGGL(sort_kernel, dim3(NBKT), dim3(512), 0, stream,
                       bufA, bstart, bufB, row_ptr);
    hipLaunchKernelGGL(pull_kernel, dim3((NN + 3) / 4), dim3(256), 0, stream,
                       gh, row_ptr, bufB, bias, out);
  } else {
    float* g = (float*)ws;
    hipLaunchKernelGGL(gemm_f32_kernel, dim3(NN / 16), dim3(256), 0, stream,
                       features, weight, g);
    hipLaunchKernelGGL(init_kernel, dim3((NN * D / 4) / 256), dim3(256), 0,
                       stream, bias, (float4*)out);
    hipLaunchKernelGGL(scatter_kernel, dim3((long)NE * 32 / 256), dim3(256), 0,
                       stream, g, norm, src, dst, out);
  }
}